// Round 15
// baseline (602.515 us; speedup 1.0000x reference)
//
#include <hip/hip_runtime.h>
#include <stdint.h>

#define HDIM 2048
#define FFND 8192
#define NHEAD 16
#define HDHEAD 128
#define TSEQ 2048
#define MTOK 4096

typedef short s16;
typedef __bf16 bf16;
typedef __attribute__((ext_vector_type(8))) __bf16 bf16x8;
typedef __attribute__((ext_vector_type(4))) float f32x4;

__device__ __forceinline__ unsigned short f2bf(float f) {
    union { float f; unsigned u; } a; a.f = f;
    unsigned r = a.u + 0x7fffu + ((a.u >> 16) & 1u);
    return (unsigned short)(r >> 16);
}

__device__ __forceinline__ void gload_lds16(const s16* g, void* l) {
    __builtin_amdgcn_global_load_lds(
        (const __attribute__((address_space(1))) void*)g,
        (__attribute__((address_space(3))) void*)l, 16, 0, 0);
}

// ---------------- transpose + fp32->bf16 convert: out[n][k] = bf16(in[k][n]) ----------------
// 64x64 tile, float4 loads, bf16x8 stores, LDS 65-stride bounce (2-way alias = free).
__global__ __launch_bounds__(256) void transpose_convert(
    const float* __restrict__ in, s16* __restrict__ out, int K, int N)
{
    __shared__ float tile[64][65];
    int n0 = blockIdx.x * 64, k0 = blockIdx.y * 64;
    int t = threadIdx.x;
    int lr = t >> 4;            // 0..15
    int lc = (t & 15) * 4;      // 0..60
    #pragma unroll
    for (int p = 0; p < 4; ++p) {
        int k = lr + p * 16;
        float4 v = *(const float4*)(in + (size_t)(k0 + k) * N + n0 + lc);
        tile[k][lc] = v.x; tile[k][lc + 1] = v.y;
        tile[k][lc + 2] = v.z; tile[k][lc + 3] = v.w;
    }
    __syncthreads();
    int orow = t >> 3;          // 0..31
    int ocol = (t & 7) * 8;     // 0..56
    #pragma unroll
    for (int p = 0; p < 2; ++p) {
        int n = orow + p * 32;
        union { s16 v[8]; bf16x8 x; } u;
        #pragma unroll
        for (int e = 0; e < 8; ++e) u.v[e] = (s16)f2bf(tile[ocol + e][n]);
        *(bf16x8*)(out + (size_t)(n0 + n) * K + k0 + ocol) = u.x;
    }
}

// ---------------- LayerNorm (fp32 in -> bf16 out), one row per block ----------------
__global__ __launch_bounds__(256) void ln_kernel(
    const float* __restrict__ x, const float* __restrict__ gam,
    const float* __restrict__ bet, s16* __restrict__ out)
{
    int row = blockIdx.x;
    int t = threadIdx.x;
    const float4* xr = (const float4*)(x + (size_t)row * HDIM);
    float4 v0 = xr[t], v1 = xr[t + 256];
    float s = v0.x + v0.y + v0.z + v0.w + v1.x + v1.y + v1.z + v1.w;
    #pragma unroll
    for (int m = 1; m < 64; m <<= 1) s += __shfl_xor(s, m);
    __shared__ float red[8];
    int wid = t >> 6, lane = t & 63;
    if (lane == 0) red[wid] = s;
    __syncthreads();
    float mean = (red[0] + red[1] + red[2] + red[3]) * (1.0f / HDIM);
    float d0 = v0.x - mean, d1 = v0.y - mean, d2 = v0.z - mean, d3 = v0.w - mean;
    float d4 = v1.x - mean, d5 = v1.y - mean, d6 = v1.z - mean, d7 = v1.w - mean;
    float vs = d0*d0 + d1*d1 + d2*d2 + d3*d3 + d4*d4 + d5*d5 + d6*d6 + d7*d7;
    #pragma unroll
    for (int m = 1; m < 64; m <<= 1) vs += __shfl_xor(vs, m);
    if (lane == 0) red[4 + wid] = vs;
    __syncthreads();
    float var = (red[4] + red[5] + red[6] + red[7]) * (1.0f / HDIM);
    float rinv = rsqrtf(var + 1e-5f);
    const float4* gm = (const float4*)gam;
    const float4* bt = (const float4*)bet;
    float4 g0 = gm[t], g1 = gm[t + 256], b0 = bt[t], b1 = bt[t + 256];
    s16* orow = out + (size_t)row * HDIM;
    float y0 = d0 * rinv * g0.x + b0.x, y1 = d1 * rinv * g0.y + b0.y;
    float y2 = d2 * rinv * g0.z + b0.z, y3 = d3 * rinv * g0.w + b0.w;
    float y4 = d4 * rinv * g1.x + b1.x, y5 = d5 * rinv * g1.y + b1.y;
    float y6 = d6 * rinv * g1.z + b1.z, y7 = d7 * rinv * g1.w + b1.w;
    uint2 o0, o1;
    o0.x = (unsigned)f2bf(y0) | ((unsigned)f2bf(y1) << 16);
    o0.y = (unsigned)f2bf(y2) | ((unsigned)f2bf(y3) << 16);
    o1.x = (unsigned)f2bf(y4) | ((unsigned)f2bf(y5) << 16);
    o1.y = (unsigned)f2bf(y6) | ((unsigned)f2bf(y7) << 16);
    *(uint2*)(orow + t * 4) = o0;
    *(uint2*)(orow + 1024 + t * 4) = o1;
}

// ============ 2-phase/K-tile BMxBN GEMM (r8-proven, byte-identical) ============
template<int BM, int BN, int EPI>
__global__ __launch_bounds__(512, 2) void gemm2p(
    const s16* __restrict__ A, const s16* __restrict__ Bt,
    const float* __restrict__ bias, int M, int N, int K,
    float* __restrict__ of, const float* __restrict__ resid,
    s16* __restrict__ ob, s16* __restrict__ ob2, s16* __restrict__ ob3)
{
    constexpr int WN  = BN / 64;
    constexpr int WM  = 8 / WN;
    constexpr int MS  = BM / WM;                  // 128|64
    constexpr int NMI = MS / 16;
    constexpr int HF  = NMI / 2;
    constexpr int ABYT = BM * 128;
    constexpr int DBUF = ABYT + BN * 128;
    constexpr bool BIG = (BM == 256 && BN == 256);
    constexpr int VMN = BIG ? 6 : (BN == 256 ? 4 : 2);
    constexpr int LG1 = BIG ? 8 : 4;
    __shared__ __attribute__((aligned(16))) char smem[2 * DBUF];

    int t = threadIdx.x;
    int wid = t >> 6, lane = t & 63;
    int wm = (WN == 4) ? (wid >> 2) : (wid >> 1);
    int wn = (WN == 4) ? (wid & 3) : (wid & 1);
    int c = lane & 15, g = lane >> 4;

    int gx = gridDim.x;
    int wg = blockIdx.y * gx + blockIdx.x;
    int nwg = gx * gridDim.y;
    wg = (wg & 7) * (nwg >> 3) + (wg >> 3);
    int n0 = (wg % gx) * BN;
    int m0 = (wg / gx) * BM;

    float bn[4];
    #pragma unroll
    for (int ni = 0; ni < 4; ++ni) bn[ni] = bias[n0 + wn * 64 + ni * 16 + c];

    int slr = t >> 3;
    int sls = (t & 7) ^ (slr & 7);
    auto stA = [&](int d, int u, int T) {
        gload_lds16(A + (size_t)(m0 + u * 64 + slr) * K + T * 64 + sls * 8,
                    smem + d * DBUF + u * 8192 + t * 16);
    };
    auto stB = [&](int d, int u, int T) {
        gload_lds16(Bt + (size_t)(n0 + u * 64 + slr) * K + T * 64 + sls * 8,
                    smem + d * DBUF + ABYT + u * 8192 + t * 16);
    };
    auto stageSB = [&](int d, int T) {
        if constexpr (BIG) {
            stA(d, 0, T); stA(d, 2, T);
            stB(d, 0, T); stB(d, 1, T); stB(d, 2, T); stB(d, 3, T);
        } else if constexpr (BN == 256) {
            stB(d, 0, T); stB(d, 1, T); stB(d, 2, T); stB(d, 3, T);
        } else {
            stB(d, 0, T); stB(d, 1, T);
        }
    };
    auto stageSA = [&](int d, int T) {
        if constexpr (BIG) { stA(d, 1, T); stA(d, 3, T); }
        else if constexpr (BN == 256) { stA(d, 0, T); stA(d, 1, T); }
        else { stA(d, 0, T); stA(d, 1, T); stA(d, 2, T); stA(d, 3, T); }
    };

    int px0 = ((g) ^ (c & 7)) * 16;
    int px1 = ((4 + g) ^ (c & 7)) * 16;

    f32x4 zero = {0.f, 0.f, 0.f, 0.f};
    f32x4 acc[NMI][4];
    #pragma unroll
    for (int mi = 0; mi < NMI; ++mi)
        #pragma unroll
        for (int ni = 0; ni < 4; ++ni) acc[mi][ni] = zero;

    bf16x8 a0[HF][2], a1[HF][2], bfr[4][2];

#define READ_B(d) { _Pragma("unroll") for (int fn = 0; fn < 4; ++fn) { \
    const char* p_ = smem + (d) * DBUF + ABYT + (wn * 64 + fn * 16 + c) * 128; \
    bfr[fn][0] = *(const bf16x8*)(p_ + px0); \
    bfr[fn][1] = *(const bf16x8*)(p_ + px1); } }
#define READ_A(d, h, arr) { _Pragma("unroll") for (int f = 0; f < HF; ++f) { \
    const char* p_ = smem + (d) * DBUF + (wm * MS + ((h) * HF + f) * 16 + c) * 128; \
    arr[f][0] = *(const bf16x8*)(p_ + px0); \
    arr[f][1] = *(const bf16x8*)(p_ + px1); } }
#define MFMA_H(h, arr) { _Pragma("unroll") for (int f = 0; f < HF; ++f) \
    _Pragma("unroll") for (int ni = 0; ni < 4; ++ni) { \
        acc[(h)*HF+f][ni] = __builtin_amdgcn_mfma_f32_16x16x32_bf16( \
            arr[f][0], bfr[ni][0], acc[(h)*HF+f][ni], 0, 0, 0); \
        acc[(h)*HF+f][ni] = __builtin_amdgcn_mfma_f32_16x16x32_bf16( \
            arr[f][1], bfr[ni][1], acc[(h)*HF+f][ni], 0, 0, 0); } }

    int nk = K >> 6;

    stageSB(0, 0);
    stageSA(0, 0);
    stageSB(1, 1);
    asm volatile("s_waitcnt vmcnt(%0)" :: "i"(VMN) : "memory");
    __builtin_amdgcn_s_barrier();

    for (int T = 0; T < nk; ++T) {
        int d = T & 1;
        bool s1 = (T + 1 < nk), s2 = (T + 2 < nk);
        __builtin_amdgcn_sched_barrier(0);
        READ_B(d) READ_A(d, 0, a0)
        __builtin_amdgcn_sched_barrier(0);
        READ_A(d, 1, a1)
        if (s1) stageSA(d ^ 1, T + 1);
        asm volatile("s_waitcnt lgkmcnt(%0)" :: "i"(LG1) : "memory");
        __builtin_amdgcn_sched_barrier(0);
        __builtin_amdgcn_s_setprio(1);
        MFMA_H(0, a0)
        __builtin_amdgcn_s_setprio(0);
        __builtin_amdgcn_s_barrier();
        __builtin_amdgcn_sched_barrier(0);
        if (s2) stageSB(d, T + 2);
        asm volatile("s_waitcnt lgkmcnt(0)" ::: "memory");
        __builtin_amdgcn_sched_barrier(0);
        __builtin_amdgcn_s_setprio(1);
        MFMA_H(1, a1)
        __builtin_amdgcn_s_setprio(0);
        if (s2) { asm volatile("s_waitcnt vmcnt(%0)" :: "i"(VMN) : "memory"); }
        else    { asm volatile("s_waitcnt vmcnt(0)" ::: "memory"); }
        __builtin_amdgcn_s_barrier();
        __builtin_amdgcn_sched_barrier(0);
    }
#undef READ_B
#undef READ_A
#undef MFMA_H

    if constexpr (EPI == 0) {
        constexpr int ROWG = BM / 64;
        int part = n0 >> 11;
        int hh0 = (n0 & 2047) >> 7;
        int bb = m0 >> 11;
        int tt0 = m0 & 2047;
        s16* LT = (s16*)smem;           // 64 x 264 bounce
        #pragma unroll
        for (int q2 = 0; q2 < ROWG; ++q2) {
            if (q2) __syncthreads();
            bool sel = (MS == 128) ? (wm == (q2 >> 1)) : (wm == q2);
            int fb = (MS == 128) ? (q2 & 1) * 4 : 0;
            if (sel) {
                #pragma unroll
                for (int f = 0; f < 4; ++f)
                    #pragma unroll
                    for (int ni = 0; ni < 4; ++ni)
                        #pragma unroll
                        for (int j = 0; j < 4; ++j)
                            LT[(f * 16 + g * 4 + j) * 264 + wn * 64 + ni * 16 + c] =
                                (s16)f2bf(acc[fb + f][ni][j] + bn[ni]);
            }
            __syncthreads();
            if (part < 2) {
                s16* dst = (part == 0 ? ob : ob2);
                int rr = t >> 3, c0 = (t & 7) * 32;
                int hh = hh0 + (c0 >> 7);
                size_t base = (((size_t)(bb * NHEAD + hh)) * TSEQ + tt0 + q2 * 64 + rr) * HDHEAD + (c0 & 127);
                #pragma unroll
                for (int k2 = 0; k2 < 4; ++k2)
                    *(bf16x8*)(dst + base + k2 * 8) = *(const bf16x8*)(LT + rr * 264 + c0 + k2 * 8);
            } else {
                int ddl = t >> 1, half = t & 1;
                int hh = hh0 + (ddl >> 7);
                size_t base = (((size_t)(bb * NHEAD + hh)) * HDHEAD + (ddl & 127)) * TSEQ + tt0 + q2 * 64 + half * 32;
                #pragma unroll
                for (int k2 = 0; k2 < 4; ++k2) {
                    union { s16 v[8]; bf16x8 x; } u;
                    #pragma unroll
                    for (int e = 0; e < 8; ++e) u.v[e] = LT[(half * 32 + k2 * 8 + e) * 264 + ddl];
                    *(bf16x8*)(ob3 + base + k2 * 8) = u.x;
                }
            }
        }
    } else {
        #pragma unroll
        for (int mi = 0; mi < NMI; ++mi) {
            #pragma unroll
            for (int ni = 0; ni < 4; ++ni) {
                int n = n0 + wn * 64 + ni * 16 + c;
                #pragma unroll
                for (int j = 0; j < 4; ++j) {
                    int m = m0 + wm * MS + mi * 16 + g * 4 + j;
                    float val = acc[mi][ni][j] + bn[ni];
                    if constexpr (EPI == 1) {
                        size_t idx = (size_t)m * N + n;
                        of[idx] = val + resid[idx];
                    } else {
                        float zz = 1.5957691216057308f * (val + 0.044715f * val * val * val);
                        float ge = val / (1.0f + __expf(-zz));
                        ob[(size_t)m * N + n] = (s16)f2bf(ge);
                    }
                }
            }
        }
    }
}

// ---------------- causal flash attention, swapped-operand (S^T = K*Q^T) ----------------
// 128 q-rows/block (8 waves); longest-first dispatch; setprio on MFMA clusters;
// T13 defer-max — skip O-rescale when per-tile max growth <= 8 (wave-uniform vote).
__global__ __launch_bounds__(512) void attn_kernel(
    const s16* __restrict__ qb, const s16* __restrict__ kbf,
    const s16* __restrict__ vbf, s16* __restrict__ yb)
{
    __shared__ __attribute__((aligned(16))) s16 Kl[64 * 128];
    __shared__ __attribute__((aligned(16))) s16 Vl[128 * 64];
    int bid0 = blockIdx.x;
    int bid = ((bid0 & 7) << 6) | (bid0 >> 3);   // XCD swizzle (512 blocks)
    int qt2 = 15 - (bid & 15);                   // descending: longest blocks first
    int bh = bid >> 4;
    int q0 = qt2 << 7;
    int t = threadIdx.x;
    int wid = t >> 6, lane = t & 63;
    int c = lane & 15, g = lane >> 4;

    const s16* qrow = qb + ((size_t)bh * TSEQ + q0 + wid * 16 + c) * HDHEAD;
    bf16x8 qf[4];
    #pragma unroll
    for (int ds = 0; ds < 4; ++ds) qf[ds] = *(const bf16x8*)(qrow + ds * 32 + g * 8);

    f32x4 zero = {0.f, 0.f, 0.f, 0.f};
    f32x4 acc_o[8];
    #pragma unroll
    for (int o = 0; o < 8; ++o) acc_o[o] = zero;
    float mrun = -INFINITY, lrun = 0.0f;
    const float sc = 0.08838834764831843f;

    int tr = t >> 4, tcb = (t & 15) << 4;   // K: 32 rows/pass x2
    int vr = t >> 3, vcb = (t & 7) << 4;    // V: 64 rows/pass x2
    const s16* ksrc = kbf + (size_t)bh * TSEQ * HDHEAD;
    const s16* vsrc = vbf + (size_t)bh * HDHEAD * TSEQ;
    int qg = q0 + wid * 16 + c;
    int ktmax = 2 * qt2 + 1;

    for (int kt = 0; kt <= ktmax; ++kt) {
        __syncthreads();
        #pragma unroll
        for (int rr = 0; rr < 2; ++rr) {
            int row = tr + rr * 32;
            bf16x8 kv = *(const bf16x8*)(ksrc + (size_t)(kt * 64 + row) * HDHEAD + (tcb >> 1));
            *(bf16x8*)((char*)Kl + row * 256 + (tcb ^ ((row & 7) << 4))) = kv;
        }
        #pragma unroll
        for (int rr = 0; rr < 2; ++rr) {
            int row = vr + rr * 64;
            bf16x8 vv = *(const bf16x8*)(vsrc + (size_t)row * TSEQ + kt * 64 + (vcb >> 1));
            *(bf16x8*)((char*)Vl + row * 128 + (vcb ^ ((row & 7) << 4))) = vv;
        }
        __syncthreads();

        f32x4 sacc[4];
        #pragma unroll
        for (int kb2 = 0; kb2 < 4; ++kb2) sacc[kb2] = zero;
        __builtin_amdgcn_s_setprio(1);
        #pragma unroll
        for (int ds = 0; ds < 4; ++ds) {
            #pragma unroll
            for (int kb2 = 0; kb2 < 4; ++kb2) {
                int krow = kb2 * 16 + c;
                bf16x8 kf = *(const bf16x8*)((char*)Kl + krow * 256 +
                                ((ds * 64 + g * 16) ^ ((krow & 7) << 4)));
                sacc[kb2] = __builtin_amdgcn_mfma_f32_16x16x32_bf16(kf, qf[ds], sacc[kb2], 0, 0, 0);
            }
        }
        __builtin_amdgcn_s_setprio(0);
        float pv[16];
        float mt = -INFINITY;
        bool diag = (kt * 64 + 63 > qg);
        #pragma unroll
        for (int kb2 = 0; kb2 < 4; ++kb2) {
            #pragma unroll
            for (int j = 0; j < 4; ++j) {
                float s = sacc[kb2][j] * sc;
                if (diag && (kt * 64 + kb2 * 16 + g * 4 + j) > qg) s = -INFINITY;
                pv[kb2 * 4 + j] = s;
                mt = fmaxf(mt, s);
            }
        }
        mt = fmaxf(mt, __shfl_xor(mt, 16));
        mt = fmaxf(mt, __shfl_xor(mt, 32));
        // T13 defer-max: rescale only when some row's max grew by > 8 (wave-uniform).
        if (!__all(mt - mrun <= 8.0f)) {
            float mnew = fmaxf(mrun, mt);
            float corr = __expf(mrun - mnew);
            #pragma unroll
            for (int o = 0; o < 8; ++o)
                #pragma unroll
                for (int j = 0; j < 4; ++j) acc_o[o][j] *= corr;
            lrun *= corr;
            mrun = mnew;
        }
        float ls = 0.0f;
        #pragma unroll
        for (int i = 0; i < 16; ++i) { float p = __expf(pv[i] - mrun); pv[i] = p; ls += p; }
        ls += __shfl_xor(ls, 16);
        ls += __shfl_xor(ls, 32);
        lrun += ls;

        unsigned dpk[8];
        #pragma unroll
        for (int kb2 = 0; kb2 < 4; ++kb2) {
            dpk[kb2 * 2]     = (unsigned)f2bf(pv[kb2 * 4 + 0]) | ((unsigned)f2bf(pv[kb2 * 4 + 1]) << 16);
            dpk[kb2 * 2 + 1] = (unsigned)f2bf(pv[kb2 * 4 + 2]) | ((unsigned)f2bf(pv[kb2 * 4 + 3]) << 16);
        }
        int srcA = ((g & 1) << 5) + c;
        int srcB = srcA + 16;
        #pragma unroll
        for (int s2 = 0; s2 < 2; ++s2) {
            unsigned lo0 = (unsigned)__shfl((int)dpk[(2 * s2) * 2 + 0], srcA);
            unsigned hi0 = (unsigned)__shfl((int)dpk[(2 * s2 + 1) * 2 + 0], srcA);
            unsigned lo1 = (unsigned)__shfl((int)dpk[(2 * s2) * 2 + 1], srcA);
            unsigned hi1 = (unsigned)__shfl((int)dpk[(2 * s2 + 1) * 2 + 1], srcA);
            unsigned lo2 = (unsigned)__shfl((int)dpk[(2 * s2) * 2 + 0], srcB);
            unsigned hi2 = (unsigned)__shfl((int)dpk[(2 * s2 + 1) * 2 + 0], srcB);
            unsigned lo3 = (unsigned)__shfl((int)dpk[(2 * s2) * 2 + 1], srcB);
            unsigned hi3 = (unsigned)__shfl((int)dpk[(2 * s2 + 1) * 2 + 1], srcB);
            union { unsigned u[4]; bf16x8 v; } pf;
            pf.u[0] = (g < 2) ? lo0 : hi0;
            pf.u[1] = (g < 2) ? lo1 : hi1;
            pf.u[2] = (g < 2) ? lo2 : hi2;
            pf.u[3] = (g < 2) ? lo3 : hi3;
            __builtin_amdgcn_s_setprio(1);
            #pragma unroll
            for (int o = 0; o < 8; ++o) {
                int vrow = o * 16 + c;
                bf16x8 vf = *(const bf16x8*)((char*)Vl + vrow * 128 +
                                ((s2 * 64 + g * 16) ^ ((vrow & 7) << 4)));
                acc_o[o] = __builtin_amdgcn_mfma_f32_16x16x32_bf16(vf, pf.v, acc_o[o], 0, 0, 0);
            }
            __builtin_amdgcn_s_setprio(0);
        }
    }

    float inv = 1.0f / lrun;
    int bb = bh >> 4, hh = bh & 15;
    s16* yp = yb + ((size_t)bb * TSEQ + q0 + wid * 16 + c) * HDIM + hh * HDHEAD;
    #pragma unroll
    for (int o = 0; o < 8; ++o) {
        int d = o * 16 + g * 4;
        unsigned p0 = (unsigned)f2bf(acc_o[o][0] * inv) | ((unsigned)f2bf(acc_o[o][1] * inv) << 16);
        unsigned p1 = (unsigned)f2bf(acc_o[o][2] * inv) | ((unsigned)f2bf(acc_o[o][3] * inv) << 16);
        *(unsigned*)(yp + d) = p0;
        *(unsigned*)(yp + d + 2) = p1;
    }
}

extern "C" void kernel_launch(void* const* d_in, const int* in_sizes, int n_in,
                              void* d_out, int out_size, void* d_ws, size_t ws_size,
                              hipStream_t stream)
{
    const float* x     = (const float*)d_in[0];
    const float* ln1g  = (const float*)d_in[1];
    const float* ln1b  = (const float*)d_in[2];
    const float* wattn = (const float*)d_in[3];
    const float* battn = (const float*)d_in[4];
    const float* wproj = (const float*)d_in[5];
    const float* bproj = (const float*)d_in[6];
    const float* ln2g  = (const float*)d_in[7];
    const float* ln2b  = (const float*)d_in[8];
    const float* wfc   = (const float*)d_in[9];
    const float* bfc   = (const float*)d_in[10];
    const float* wfc2  = (const float*)d_in[11];
    const float* bfc2  = (const float*)d_in[12];
    float* out = (float*)d_out;

    s16* ws   = (s16*)d_ws;
    s16* wT   = ws;                        // 16,777,216 elems (max weight^T)
    s16* qbuf = wT + 16777216;             // 8,388,608
    s16* kbuf = qbuf + 8388608;            // 8,388,608
    s16* vbuf = kbuf + 8388608;            // 8,388,608 (transposed V)
    s16* hbuf = vbuf + 8388608;            // 8,388,608 (LN1 out; reused as attn y)
    s16* ybuf  = hbuf;
    s16* h2buf = qbuf;
    s16* gbuf  = kbuf;

    // 1) LN1
    ln_kernel<<<4096, 256, 0, stream>>>(x, ln1g, ln1b, hbuf);
    // 2) QKV GEMM: (128,256) 2-phase, grid 768 = 3 blocks/CU (scatter q/k/v, v transposed)
    transpose_convert<<<dim3(96, 32), 256, 0, stream>>>(wattn, wT, 2048, 6144);
    gemm2p<128, 256, 0><<<dim3(24, 32), 512, 0, stream>>>(
        hbuf, wT, battn, MTOK, 6144, 2048, nullptr, nullptr, qbuf, kbuf, vbuf);
    // 3) attention: 512 blocks x 512 thr, 128 q-rows/block, longest-first, defer-max
    attn_kernel<<<512, 512, 0, stream>>>(qbuf, kbuf, vbuf, ybuf);
    // 4) proj (+residual, fp32 -> d_out)
    transpose_convert<<<dim3(32, 32), 256, 0, stream>>>(wproj, wT, 2048, 2048);
    gemm2p<256, 128, 1><<<dim3(16, 16), 512, 0, stream>>>(
        ybuf, wT, bproj, MTOK, 2048, 2048, out, x, nullptr, nullptr, nullptr);
    // 5) LN2
    ln_kernel<<<4096, 256, 0, stream>>>(out, ln2g, ln2b, h2buf);
    // 6) fc (+gelu, bf16)
    transpose_convert<<<dim3(128, 32), 256, 0, stream>>>(wfc, wT, 2048, 8192);
    gemm2p<256, 256, 2><<<dim3(32, 16), 512, 0, stream>>>(
        h2buf, wT, bfc, MTOK, 8192, 2048, nullptr, nullptr, gbuf, nullptr, nullptr);
    // 7) fc2 (+residual, fp32; reads+overwrites d_out per-element)
    transpose_convert<<<dim3(32, 128), 256, 0, stream>>>(wfc2, wT, 8192, 2048);
    gemm2p<256, 128, 1><<<dim3(16, 16), 512, 0, stream>>>(
        gbuf, wT, bfc2, MTOK, 2048, 8192, out, out, nullptr, nullptr, nullptr);
}

// Round 16
// 565.777 us; speedup vs baseline: 1.0649x; 1.0649x over previous
//
#include <hip/hip_runtime.h>
#include <stdint.h>

#define HDIM 2048
#define FFND 8192
#define NHEAD 16
#define HDHEAD 128
#define TSEQ 2048
#define MTOK 4096

typedef short s16;
typedef __bf16 bf16;
typedef __attribute__((ext_vector_type(8))) __bf16 bf16x8;
typedef __attribute__((ext_vector_type(4))) float f32x4;

__device__ __forceinline__ unsigned short f2bf(float f) {
    union { float f; unsigned u; } a; a.f = f;
    unsigned r = a.u + 0x7fffu + ((a.u >> 16) & 1u);
    return (unsigned short)(r >> 16);
}

__device__ __forceinline__ void gload_lds16(const s16* g, void* l) {
    __builtin_amdgcn_global_load_lds(
        (const __attribute__((address_space(1))) void*)g,
        (__attribute__((address_space(3))) void*)l, 16, 0, 0);
}

// ---------------- transpose + fp32->bf16 convert (256 thr standalone) ----------------
__global__ __launch_bounds__(256) void transpose_convert(
    const float* __restrict__ in, s16* __restrict__ out, int K, int N)
{
    __shared__ float tile[64][65];
    int n0 = blockIdx.x * 64, k0 = blockIdx.y * 64;
    int t = threadIdx.x;
    int lr = t >> 4;            // 0..15
    int lc = (t & 15) * 4;      // 0..60
    #pragma unroll
    for (int p = 0; p < 4; ++p) {
        int k = lr + p * 16;
        float4 v = *(const float4*)(in + (size_t)(k0 + k) * N + n0 + lc);
        tile[k][lc] = v.x; tile[k][lc + 1] = v.y;
        tile[k][lc + 2] = v.z; tile[k][lc + 3] = v.w;
    }
    __syncthreads();
    int orow = t >> 3;          // 0..31
    int ocol = (t & 7) * 8;     // 0..56
    #pragma unroll
    for (int p = 0; p < 2; ++p) {
        int n = orow + p * 32;
        union { s16 v[8]; bf16x8 x; } u;
        #pragma unroll
        for (int e = 0; e < 8; ++e) u.v[e] = (s16)f2bf(tile[ocol + e][n]);
        *(bf16x8*)(out + (size_t)(n0 + n) * K + k0 + ocol) = u.x;
    }
}

// 512-thread transpose tile worker (fused into attn launch)
__device__ __forceinline__ void transpose512(
    const float* __restrict__ in, s16* __restrict__ out, int K, int N,
    int tile_id, float (*tile)[65])
{
    int ntn = N >> 6;
    int n0 = (tile_id % ntn) * 64, k0 = (tile_id / ntn) * 64;
    int t = threadIdx.x;
    int lr = t >> 4;            // 0..31
    int lc = (t & 15) * 4;
    #pragma unroll
    for (int p = 0; p < 2; ++p) {
        int k = lr + p * 32;
        float4 v = *(const float4*)(in + (size_t)(k0 + k) * N + n0 + lc);
        tile[k][lc] = v.x; tile[k][lc + 1] = v.y;
        tile[k][lc + 2] = v.z; tile[k][lc + 3] = v.w;
    }
    __syncthreads();
    int orow = t >> 3;          // 0..63
    int ocol = (t & 7) * 8;
    union { s16 v[8]; bf16x8 x; } u;
    #pragma unroll
    for (int e = 0; e < 8; ++e) u.v[e] = (s16)f2bf(tile[ocol + e][orow]);
    *(bf16x8*)(out + (size_t)(n0 + orow) * K + k0 + ocol) = u.x;
}

// ---------------- LayerNorm (fp32 in -> bf16 out), one row per block ----------------
__global__ __launch_bounds__(256) void ln_kernel(
    const float* __restrict__ x, const float* __restrict__ gam,
    const float* __restrict__ bet, s16* __restrict__ out)
{
    int row = blockIdx.x;
    int t = threadIdx.x;
    const float4* xr = (const float4*)(x + (size_t)row * HDIM);
    float4 v0 = xr[t], v1 = xr[t + 256];
    float s = v0.x + v0.y + v0.z + v0.w + v1.x + v1.y + v1.z + v1.w;
    #pragma unroll
    for (int m = 1; m < 64; m <<= 1) s += __shfl_xor(s, m);
    __shared__ float red[8];
    int wid = t >> 6, lane = t & 63;
    if (lane == 0) red[wid] = s;
    __syncthreads();
    float mean = (red[0] + red[1] + red[2] + red[3]) * (1.0f / HDIM);
    float d0 = v0.x - mean, d1 = v0.y - mean, d2 = v0.z - mean, d3 = v0.w - mean;
    float d4 = v1.x - mean, d5 = v1.y - mean, d6 = v1.z - mean, d7 = v1.w - mean;
    float vs = d0*d0 + d1*d1 + d2*d2 + d3*d3 + d4*d4 + d5*d5 + d6*d6 + d7*d7;
    #pragma unroll
    for (int m = 1; m < 64; m <<= 1) vs += __shfl_xor(vs, m);
    if (lane == 0) red[4 + wid] = vs;
    __syncthreads();
    float var = (red[4] + red[5] + red[6] + red[7]) * (1.0f / HDIM);
    float rinv = rsqrtf(var + 1e-5f);
    const float4* gm = (const float4*)gam;
    const float4* bt = (const float4*)bet;
    float4 g0 = gm[t], g1 = gm[t + 256], b0 = bt[t], b1 = bt[t + 256];
    s16* orow = out + (size_t)row * HDIM;
    float y0 = d0 * rinv * g0.x + b0.x, y1 = d1 * rinv * g0.y + b0.y;
    float y2 = d2 * rinv * g0.z + b0.z, y3 = d3 * rinv * g0.w + b0.w;
    float y4 = d4 * rinv * g1.x + b1.x, y5 = d5 * rinv * g1.y + b1.y;
    float y6 = d6 * rinv * g1.z + b1.z, y7 = d7 * rinv * g1.w + b1.w;
    uint2 o0, o1;
    o0.x = (unsigned)f2bf(y0) | ((unsigned)f2bf(y1) << 16);
    o0.y = (unsigned)f2bf(y2) | ((unsigned)f2bf(y3) << 16);
    o1.x = (unsigned)f2bf(y4) | ((unsigned)f2bf(y5) << 16);
    o1.y = (unsigned)f2bf(y6) | ((unsigned)f2bf(y7) << 16);
    *(uint2*)(orow + t * 4) = o0;
    *(uint2*)(orow + 1024 + t * 4) = o1;
}

// ============ 2-phase/K-tile BMxBN GEMM (r8-proven, byte-identical) ============
template<int BM, int BN, int EPI>
__global__ __launch_bounds__(512, 2) void gemm2p(
    const s16* __restrict__ A, const s16* __restrict__ Bt,
    const float* __restrict__ bias, int M, int N, int K,
    float* __restrict__ of, const float* __restrict__ resid,
    s16* __restrict__ ob, s16* __restrict__ ob2, s16* __restrict__ ob3)
{
    constexpr int WN  = BN / 64;
    constexpr int WM  = 8 / WN;
    constexpr int MS  = BM / WM;                  // 128|64
    constexpr int NMI = MS / 16;
    constexpr int HF  = NMI / 2;
    constexpr int ABYT = BM * 128;
    constexpr int DBUF = ABYT + BN * 128;
    constexpr bool BIG = (BM == 256 && BN == 256);
    constexpr int VMN = BIG ? 6 : (BN == 256 ? 4 : 2);
    constexpr int LG1 = BIG ? 8 : 4;
    __shared__ __attribute__((aligned(16))) char smem[2 * DBUF];

    int t = threadIdx.x;
    int wid = t >> 6, lane = t & 63;
    int wm = (WN == 4) ? (wid >> 2) : (wid >> 1);
    int wn = (WN == 4) ? (wid & 3) : (wid & 1);
    int c = lane & 15, g = lane >> 4;

    int gx = gridDim.x;
    int wg = blockIdx.y * gx + blockIdx.x;
    int nwg = gx * gridDim.y;
    wg = (wg & 7) * (nwg >> 3) + (wg >> 3);
    int n0 = (wg % gx) * BN;
    int m0 = (wg / gx) * BM;

    float bn[4];
    #pragma unroll
    for (int ni = 0; ni < 4; ++ni) bn[ni] = bias[n0 + wn * 64 + ni * 16 + c];

    int slr = t >> 3;
    int sls = (t & 7) ^ (slr & 7);
    auto stA = [&](int d, int u, int T) {
        gload_lds16(A + (size_t)(m0 + u * 64 + slr) * K + T * 64 + sls * 8,
                    smem + d * DBUF + u * 8192 + t * 16);
    };
    auto stB = [&](int d, int u, int T) {
        gload_lds16(Bt + (size_t)(n0 + u * 64 + slr) * K + T * 64 + sls * 8,
                    smem + d * DBUF + ABYT + u * 8192 + t * 16);
    };
    auto stageSB = [&](int d, int T) {
        if constexpr (BIG) {
            stA(d, 0, T); stA(d, 2, T);
            stB(d, 0, T); stB(d, 1, T); stB(d, 2, T); stB(d, 3, T);
        } else if constexpr (BN == 256) {
            stB(d, 0, T); stB(d, 1, T); stB(d, 2, T); stB(d, 3, T);
        } else {
            stB(d, 0, T); stB(d, 1, T);
        }
    };
    auto stageSA = [&](int d, int T) {
        if constexpr (BIG) { stA(d, 1, T); stA(d, 3, T); }
        else if constexpr (BN == 256) { stA(d, 0, T); stA(d, 1, T); }
        else { stA(d, 0, T); stA(d, 1, T); stA(d, 2, T); stA(d, 3, T); }
    };

    int px0 = ((g) ^ (c & 7)) * 16;
    int px1 = ((4 + g) ^ (c & 7)) * 16;

    f32x4 zero = {0.f, 0.f, 0.f, 0.f};
    f32x4 acc[NMI][4];
    #pragma unroll
    for (int mi = 0; mi < NMI; ++mi)
        #pragma unroll
        for (int ni = 0; ni < 4; ++ni) acc[mi][ni] = zero;

    bf16x8 a0[HF][2], a1[HF][2], bfr[4][2];

#define READ_B(d) { _Pragma("unroll") for (int fn = 0; fn < 4; ++fn) { \
    const char* p_ = smem + (d) * DBUF + ABYT + (wn * 64 + fn * 16 + c) * 128; \
    bfr[fn][0] = *(const bf16x8*)(p_ + px0); \
    bfr[fn][1] = *(const bf16x8*)(p_ + px1); } }
#define READ_A(d, h, arr) { _Pragma("unroll") for (int f = 0; f < HF; ++f) { \
    const char* p_ = smem + (d) * DBUF + (wm * MS + ((h) * HF + f) * 16 + c) * 128; \
    arr[f][0] = *(const bf16x8*)(p_ + px0); \
    arr[f][1] = *(const bf16x8*)(p_ + px1); } }
#define MFMA_H(h, arr) { _Pragma("unroll") for (int f = 0; f < HF; ++f) \
    _Pragma("unroll") for (int ni = 0; ni < 4; ++ni) { \
        acc[(h)*HF+f][ni] = __builtin_amdgcn_mfma_f32_16x16x32_bf16( \
            arr[f][0], bfr[ni][0], acc[(h)*HF+f][ni], 0, 0, 0); \
        acc[(h)*HF+f][ni] = __builtin_amdgcn_mfma_f32_16x16x32_bf16( \
            arr[f][1], bfr[ni][1], acc[(h)*HF+f][ni], 0, 0, 0); } }

    int nk = K >> 6;

    stageSB(0, 0);
    stageSA(0, 0);
    stageSB(1, 1);
    asm volatile("s_waitcnt vmcnt(%0)" :: "i"(VMN) : "memory");
    __builtin_amdgcn_s_barrier();

    for (int T = 0; T < nk; ++T) {
        int d = T & 1;
        bool s1 = (T + 1 < nk), s2 = (T + 2 < nk);
        __builtin_amdgcn_sched_barrier(0);
        READ_B(d) READ_A(d, 0, a0)
        __builtin_amdgcn_sched_barrier(0);
        READ_A(d, 1, a1)
        if (s1) stageSA(d ^ 1, T + 1);
        asm volatile("s_waitcnt lgkmcnt(%0)" :: "i"(LG1) : "memory");
        __builtin_amdgcn_sched_barrier(0);
        __builtin_amdgcn_s_setprio(1);
        MFMA_H(0, a0)
        __builtin_amdgcn_s_setprio(0);
        __builtin_amdgcn_s_barrier();
        __builtin_amdgcn_sched_barrier(0);
        if (s2) stageSB(d, T + 2);
        asm volatile("s_waitcnt lgkmcnt(0)" ::: "memory");
        __builtin_amdgcn_sched_barrier(0);
        __builtin_amdgcn_s_setprio(1);
        MFMA_H(1, a1)
        __builtin_amdgcn_s_setprio(0);
        if (s2) { asm volatile("s_waitcnt vmcnt(%0)" :: "i"(VMN) : "memory"); }
        else    { asm volatile("s_waitcnt vmcnt(0)" ::: "memory"); }
        __builtin_amdgcn_s_barrier();
        __builtin_amdgcn_sched_barrier(0);
    }
#undef READ_B
#undef READ_A
#undef MFMA_H

    if constexpr (EPI == 0) {
        constexpr int ROWG = BM / 64;
        int part = n0 >> 11;
        int hh0 = (n0 & 2047) >> 7;
        int bb = m0 >> 11;
        int tt0 = m0 & 2047;
        s16* LT = (s16*)smem;           // 64 x 264 bounce
        #pragma unroll
        for (int q2 = 0; q2 < ROWG; ++q2) {
            if (q2) __syncthreads();
            bool sel = (MS == 128) ? (wm == (q2 >> 1)) : (wm == q2);
            int fb = (MS == 128) ? (q2 & 1) * 4 : 0;
            if (sel) {
                #pragma unroll
                for (int f = 0; f < 4; ++f)
                    #pragma unroll
                    for (int ni = 0; ni < 4; ++ni)
                        #pragma unroll
                        for (int j = 0; j < 4; ++j)
                            LT[(f * 16 + g * 4 + j) * 264 + wn * 64 + ni * 16 + c] =
                                (s16)f2bf(acc[fb + f][ni][j] + bn[ni]);
            }
            __syncthreads();
            if (part < 2) {
                s16* dst = (part == 0 ? ob : ob2);
                int rr = t >> 3, c0 = (t & 7) * 32;
                int hh = hh0 + (c0 >> 7);
                size_t base = (((size_t)(bb * NHEAD + hh)) * TSEQ + tt0 + q2 * 64 + rr) * HDHEAD + (c0 & 127);
                #pragma unroll
                for (int k2 = 0; k2 < 4; ++k2)
                    *(bf16x8*)(dst + base + k2 * 8) = *(const bf16x8*)(LT + rr * 264 + c0 + k2 * 8);
            } else {
                int ddl = t >> 1, half = t & 1;
                int hh = hh0 + (ddl >> 7);
                size_t base = (((size_t)(bb * NHEAD + hh)) * HDHEAD + (ddl & 127)) * TSEQ + tt0 + q2 * 64 + half * 32;
                #pragma unroll
                for (int k2 = 0; k2 < 4; ++k2) {
                    union { s16 v[8]; bf16x8 x; } u;
                    #pragma unroll
                    for (int e = 0; e < 8; ++e) u.v[e] = LT[(half * 32 + k2 * 8 + e) * 264 + ddl];
                    *(bf16x8*)(ob3 + base + k2 * 8) = u.x;
                }
            }
        }
    } else {
        #pragma unroll
        for (int mi = 0; mi < NMI; ++mi) {
            #pragma unroll
            for (int ni = 0; ni < 4; ++ni) {
                int n = n0 + wn * 64 + ni * 16 + c;
                #pragma unroll
                for (int j = 0; j < 4; ++j) {
                    int m = m0 + wm * MS + mi * 16 + g * 4 + j;
                    float val = acc[mi][ni][j] + bn[ni];
                    if constexpr (EPI == 1) {
                        size_t idx = (size_t)m * N + n;
                        of[idx] = val + resid[idx];
                    } else {
                        float zz = 1.5957691216057308f * (val + 0.044715f * val * val * val);
                        float ge = val / (1.0f + __expf(-zz));
                        ob[(size_t)m * N + n] = (s16)f2bf(ge);
                    }
                }
            }
        }
    }
}

// ---------------- causal flash attention + fused weight transposes ----------------
// Blocks 0..511: attention (r13-identical). Blocks 512+: transpose tiles
// for w_proj (n1), w_fc (n2), w_fc2 (rest). Transpose-block LDS reuses the K/V buffer.
__global__ __launch_bounds__(512) void attn_kernel(
    const s16* __restrict__ qb, const s16* __restrict__ kbf,
    const s16* __restrict__ vbf, s16* __restrict__ yb,
    const float* __restrict__ w1, s16* __restrict__ w1T, int n1,
    const float* __restrict__ w2, s16* __restrict__ w2T, int n2,
    const float* __restrict__ w3, s16* __restrict__ w3T)
{
    __shared__ __attribute__((aligned(16))) char sm[32768];
    s16* Kl = (s16*)sm;
    s16* Vl = (s16*)(sm + 16384);
    int fid = blockIdx.x;
    if (fid >= 512) {
        float (*tile)[65] = (float (*)[65])sm;
        fid -= 512;
        if (fid < n1)           transpose512(w1, w1T, 2048, 2048, fid, tile);
        else if (fid < n1 + n2) transpose512(w2, w2T, 2048, 8192, fid - n1, tile);
        else                    transpose512(w3, w3T, 8192, 2048, fid - n1 - n2, tile);
        return;
    }
    int bid = ((fid & 7) << 6) | (fid >> 3);     // XCD swizzle (512 blocks)
    int qt2 = 15 - (bid & 15);                   // descending: longest blocks first
    int bh = bid >> 4;
    int q0 = qt2 << 7;
    int t = threadIdx.x;
    int wid = t >> 6, lane = t & 63;
    int c = lane & 15, g = lane >> 4;

    const s16* qrow = qb + ((size_t)bh * TSEQ + q0 + wid * 16 + c) * HDHEAD;
    bf16x8 qf[4];
    #pragma unroll
    for (int ds = 0; ds < 4; ++ds) qf[ds] = *(const bf16x8*)(qrow + ds * 32 + g * 8);

    f32x4 zero = {0.f, 0.f, 0.f, 0.f};
    f32x4 acc_o[8];
    #pragma unroll
    for (int o = 0; o < 8; ++o) acc_o[o] = zero;
    float mrun = -INFINITY, lrun = 0.0f;
    const float sc = 0.08838834764831843f;

    int tr = t >> 4, tcb = (t & 15) << 4;
    int vr = t >> 3, vcb = (t & 7) << 4;
    const s16* ksrc = kbf + (size_t)bh * TSEQ * HDHEAD;
    const s16* vsrc = vbf + (size_t)bh * HDHEAD * TSEQ;
    int qg = q0 + wid * 16 + c;
    int ktmax = 2 * qt2 + 1;

    for (int kt = 0; kt <= ktmax; ++kt) {
        __syncthreads();
        #pragma unroll
        for (int rr = 0; rr < 2; ++rr) {
            int row = tr + rr * 32;
            bf16x8 kv = *(const bf16x8*)(ksrc + (size_t)(kt * 64 + row) * HDHEAD + (tcb >> 1));
            *(bf16x8*)((char*)Kl + row * 256 + (tcb ^ ((row & 7) << 4))) = kv;
        }
        #pragma unroll
        for (int rr = 0; rr < 2; ++rr) {
            int row = vr + rr * 64;
            bf16x8 vv = *(const bf16x8*)(vsrc + (size_t)row * TSEQ + kt * 64 + (vcb >> 1));
            *(bf16x8*)((char*)Vl + row * 128 + (vcb ^ ((row & 7) << 4))) = vv;
        }
        __syncthreads();

        f32x4 sacc[4];
        #pragma unroll
        for (int kb2 = 0; kb2 < 4; ++kb2) sacc[kb2] = zero;
        __builtin_amdgcn_s_setprio(1);
        #pragma unroll
        for (int ds = 0; ds < 4; ++ds) {
            #pragma unroll
            for (int kb2 = 0; kb2 < 4; ++kb2) {
                int krow = kb2 * 16 + c;
                bf16x8 kf = *(const bf16x8*)((char*)Kl + krow * 256 +
                                ((ds * 64 + g * 16) ^ ((krow & 7) << 4)));
                sacc[kb2] = __builtin_amdgcn_mfma_f32_16x16x32_bf16(kf, qf[ds], sacc[kb2], 0, 0, 0);
            }
        }
        __builtin_amdgcn_s_setprio(0);
        float pv[16];
        float mt = -INFINITY;
        bool diag = (kt * 64 + 63 > qg);
        #pragma unroll
        for (int kb2 = 0; kb2 < 4; ++kb2) {
            #pragma unroll
            for (int j = 0; j < 4; ++j) {
                float s = sacc[kb2][j] * sc;
                if (diag && (kt * 64 + kb2 * 16 + g * 4 + j) > qg) s = -INFINITY;
                pv[kb2 * 4 + j] = s;
                mt = fmaxf(mt, s);
            }
        }
        mt = fmaxf(mt, __shfl_xor(mt, 16));
        mt = fmaxf(mt, __shfl_xor(mt, 32));
        if (!__all(mt - mrun <= 8.0f)) {
            float mnew = fmaxf(mrun, mt);
            float corr = __expf(mrun - mnew);
            #pragma unroll
            for (int o = 0; o < 8; ++o)
                #pragma unroll
                for (int j = 0; j < 4; ++j) acc_o[o][j] *= corr;
            lrun *= corr;
            mrun = mnew;
        }
        float ls = 0.0f;
        #pragma unroll
        for (int i = 0; i < 16; ++i) { float p = __expf(pv[i] - mrun); pv[i] = p; ls += p; }
        ls += __shfl_xor(ls, 16);
        ls += __shfl_xor(ls, 32);
        lrun += ls;

        unsigned dpk[8];
        #pragma unroll
        for (int kb2 = 0; kb2 < 4; ++kb2) {
            dpk[kb2 * 2]     = (unsigned)f2bf(pv[kb2 * 4 + 0]) | ((unsigned)f2bf(pv[kb2 * 4 + 1]) << 16);
            dpk[kb2 * 2 + 1] = (unsigned)f2bf(pv[kb2 * 4 + 2]) | ((unsigned)f2bf(pv[kb2 * 4 + 3]) << 16);
        }
        int srcA = ((g & 1) << 5) + c;
        int srcB = srcA + 16;
        #pragma unroll
        for (int s2 = 0; s2 < 2; ++s2) {
            unsigned lo0 = (unsigned)__shfl((int)dpk[(2 * s2) * 2 + 0], srcA);
            unsigned hi0 = (unsigned)__shfl((int)dpk[(2 * s2 + 1) * 2 + 0], srcA);
            unsigned lo1 = (unsigned)__shfl((int)dpk[(2 * s2) * 2 + 1], srcA);
            unsigned hi1 = (unsigned)__shfl((int)dpk[(2 * s2 + 1) * 2 + 1], srcA);
            unsigned lo2 = (unsigned)__shfl((int)dpk[(2 * s2) * 2 + 0], srcB);
            unsigned hi2 = (unsigned)__shfl((int)dpk[(2 * s2 + 1) * 2 + 0], srcB);
            unsigned lo3 = (unsigned)__shfl((int)dpk[(2 * s2) * 2 + 1], srcB);
            unsigned hi3 = (unsigned)__shfl((int)dpk[(2 * s2 + 1) * 2 + 1], srcB);
            union { unsigned u[4]; bf16x8 v; } pf;
            pf.u[0] = (g < 2) ? lo0 : hi0;
            pf.u[1] = (g < 2) ? lo1 : hi1;
            pf.u[2] = (g < 2) ? lo2 : hi2;
            pf.u[3] = (g < 2) ? lo3 : hi3;
            __builtin_amdgcn_s_setprio(1);
            #pragma unroll
            for (int o = 0; o < 8; ++o) {
                int vrow = o * 16 + c;
                bf16x8 vf = *(const bf16x8*)((char*)Vl + vrow * 128 +
                                ((s2 * 64 + g * 16) ^ ((vrow & 7) << 4)));
                acc_o[o] = __builtin_amdgcn_mfma_f32_16x16x32_bf16(vf, pf.v, acc_o[o], 0, 0, 0);
            }
            __builtin_amdgcn_s_setprio(0);
        }
    }

    float inv = 1.0f / lrun;
    int bb = bh >> 4, hh = bh & 15;
    s16* yp = yb + ((size_t)bb * TSEQ + q0 + wid * 16 + c) * HDIM + hh * HDHEAD;
    #pragma unroll
    for (int o = 0; o < 8; ++o) {
        int d = o * 16 + g * 4;
        unsigned p0 = (unsigned)f2bf(acc_o[o][0] * inv) | ((unsigned)f2bf(acc_o[o][1] * inv) << 16);
        unsigned p1 = (unsigned)f2bf(acc_o[o][2] * inv) | ((unsigned)f2bf(acc_o[o][3] * inv) << 16);
        *(unsigned*)(yp + d) = p0;
        *(unsigned*)(yp + d + 2) = p1;
    }
}

extern "C" void kernel_launch(void* const* d_in, const int* in_sizes, int n_in,
                              void* d_out, int out_size, void* d_ws, size_t ws_size,
                              hipStream_t stream)
{
    const float* x     = (const float*)d_in[0];
    const float* ln1g  = (const float*)d_in[1];
    const float* ln1b  = (const float*)d_in[2];
    const float* wattn = (const float*)d_in[3];
    const float* battn = (const float*)d_in[4];
    const float* wproj = (const float*)d_in[5];
    const float* bproj = (const float*)d_in[6];
    const float* ln2g  = (const float*)d_in[7];
    const float* ln2b  = (const float*)d_in[8];
    const float* wfc   = (const float*)d_in[9];
    const float* bfc   = (const float*)d_in[10];
    const float* wfc2  = (const float*)d_in[11];
    const float* bfc2  = (const float*)d_in[12];
    float* out = (float*)d_out;

    s16* ws   = (s16*)d_ws;
    s16* wT   = ws;                        // [0, 16777216): w_attn^T, then w_fc^T
    s16* qbuf = wT + 16777216;             // [16777216, 25165824)
    s16* kbuf = qbuf + 8388608;            // [25165824, 33554432)
    s16* vbuf = kbuf + 8388608;            // [33554432, 41943040)
    s16* hbuf = vbuf + 8388608;            // [41943040, 50331648)
    s16* ybuf  = hbuf;
    s16* h2buf = qbuf;
    s16* gbuf  = kbuf;                     // gelu out spans [25165824, 58720256)

    // Overlap layout (r16 fix): wTp inside gbuf tail (consumed at proj, BEFORE fc
    // writes gbuf); wTf2 BEYOND gbuf end (survives until fc2).
    const size_t NEED = (58720256ull + 16777216ull) * 2;   // 151.0 MB
    bool big = (ws_size >= NEED);
    s16* wTp  = big ? hbuf + 8388608 : wT;   // [50331648, 54525952)
    s16* wTf2 = big ? ws + 58720256  : wT;   // [58720256, 75497472) — disjoint from gbuf
    s16* wTfc = wT;                          // w_attn^T slot, dead after QKV

    // 1) LN1
    ln_kernel<<<4096, 256, 0, stream>>>(x, ln1g, ln1b, hbuf);
    // 2) w_attn^T then QKV GEMM (scatter q/k/v, v transposed)
    transpose_convert<<<dim3(96, 32), 256, 0, stream>>>(wattn, wT, 2048, 6144);
    gemm2p<128, 256, 0><<<dim3(24, 32), 512, 0, stream>>>(
        hbuf, wT, battn, MTOK, 6144, 2048, nullptr, nullptr, qbuf, kbuf, vbuf);
    // 3) attention (+ fused w_proj/w_fc/w_fc2 transposes when ws allows)
    if (big) {
        attn_kernel<<<512 + 1024 + 4096 + 4096, 512, 0, stream>>>(
            qbuf, kbuf, vbuf, ybuf,
            wproj, wTp, 1024, wfc, wTfc, 4096, wfc2, wTf2);
    } else {
        attn_kernel<<<512, 512, 0, stream>>>(
            qbuf, kbuf, vbuf, ybuf,
            nullptr, nullptr, 0, nullptr, nullptr, 0, nullptr, nullptr);
    }
    // 4) proj (+residual, fp32 -> d_out)
    if (!big) transpose_convert<<<dim3(32, 32), 256, 0, stream>>>(wproj, wTp, 2048, 2048);
    gemm2p<256, 128, 1><<<dim3(16, 16), 512, 0, stream>>>(
        ybuf, wTp, bproj, MTOK, 2048, 2048, out, x, nullptr, nullptr, nullptr);
    // 5) LN2
    ln_kernel<<<4096, 256, 0, stream>>>(out, ln2g, ln2b, h2buf);
    // 6) fc (+gelu, bf16) — writes gbuf over [25165824, 58720256)
    if (!big) transpose_convert<<<dim3(128, 32), 256, 0, stream>>>(wfc, wTfc, 2048, 8192);
    gemm2p<256, 256, 2><<<dim3(32, 16), 512, 0, stream>>>(
        h2buf, wTfc, bfc, MTOK, 8192, 2048, nullptr, nullptr, gbuf, nullptr, nullptr);
    // 7) fc2 (+residual, fp32; reads+overwrites d_out per-element)
    if (!big) transpose_convert<<<dim3(32, 128), 256, 0, stream>>>(wfc2, wTf2, 8192, 2048);
    gemm2p<256, 128, 1><<<dim3(16, 16), 512, 0, stream>>>(
        gbuf, wTf2, bfc2, MTOK, 2048, 8192, out, out, nullptr, nullptr, nullptr);
}

// Round 17
// 564.370 us; speedup vs baseline: 1.0676x; 1.0025x over previous
//
#include <hip/hip_runtime.h>
#include <stdint.h>

#define HDIM 2048
#define FFND 8192
#define NHEAD 16
#define HDHEAD 128
#define TSEQ 2048
#define MTOK 4096

typedef short s16;
typedef __bf16 bf16;
typedef __attribute__((ext_vector_type(8))) __bf16 bf16x8;
typedef __attribute__((ext_vector_type(4))) float f32x4;

__device__ __forceinline__ unsigned short f2bf(float f) {
    union { float f; unsigned u; } a; a.f = f;
    unsigned r = a.u + 0x7fffu + ((a.u >> 16) & 1u);
    return (unsigned short)(r >> 16);
}

__device__ __forceinline__ void gload_lds16(const s16* g, void* l) {
    __builtin_amdgcn_global_load_lds(
        (const __attribute__((address_space(1))) void*)g,
        (__attribute__((address_space(3))) void*)l, 16, 0, 0);
}

// ---------------- 256-thr transpose tile body (shared by standalone + fused) ----------------
__device__ __forceinline__ void transpose_body256(
    const float* __restrict__ in, s16* __restrict__ out, int K, int N,
    int n0, int k0, float (*tile)[65])
{
    int t = threadIdx.x;
    int lr = t >> 4;            // 0..15
    int lc = (t & 15) * 4;      // 0..60
    #pragma unroll
    for (int p = 0; p < 4; ++p) {
        int k = lr + p * 16;
        float4 v = *(const float4*)(in + (size_t)(k0 + k) * N + n0 + lc);
        tile[k][lc] = v.x; tile[k][lc + 1] = v.y;
        tile[k][lc + 2] = v.z; tile[k][lc + 3] = v.w;
    }
    __syncthreads();
    int orow = t >> 3;          // 0..31
    int ocol = (t & 7) * 8;     // 0..56
    #pragma unroll
    for (int p = 0; p < 2; ++p) {
        int n = orow + p * 32;
        union { s16 v[8]; bf16x8 x; } u;
        #pragma unroll
        for (int e = 0; e < 8; ++e) u.v[e] = (s16)f2bf(tile[ocol + e][n]);
        *(bf16x8*)(out + (size_t)(n0 + n) * K + k0 + ocol) = u.x;
    }
}

__global__ __launch_bounds__(256) void transpose_convert(
    const float* __restrict__ in, s16* __restrict__ out, int K, int N)
{
    __shared__ float tile[64][65];
    transpose_body256(in, out, K, N, blockIdx.x * 64, blockIdx.y * 64, tile);
}

// 512-thread transpose tile worker (fused into attn launch)
__device__ __forceinline__ void transpose512(
    const float* __restrict__ in, s16* __restrict__ out, int K, int N,
    int tile_id, float (*tile)[65])
{
    int ntn = N >> 6;
    int n0 = (tile_id % ntn) * 64, k0 = (tile_id / ntn) * 64;
    int t = threadIdx.x;
    int lr = t >> 4;            // 0..31
    int lc = (t & 15) * 4;
    #pragma unroll
    for (int p = 0; p < 2; ++p) {
        int k = lr + p * 32;
        float4 v = *(const float4*)(in + (size_t)(k0 + k) * N + n0 + lc);
        tile[k][lc] = v.x; tile[k][lc + 1] = v.y;
        tile[k][lc + 2] = v.z; tile[k][lc + 3] = v.w;
    }
    __syncthreads();
    int orow = t >> 3;          // 0..63
    int ocol = (t & 7) * 8;
    union { s16 v[8]; bf16x8 x; } u;
    #pragma unroll
    for (int e = 0; e < 8; ++e) u.v[e] = (s16)f2bf(tile[ocol + e][orow]);
    *(bf16x8*)(out + (size_t)(n0 + orow) * K + k0 + ocol) = u.x;
}

// ---------------- LayerNorm body (fp32 in -> bf16 out), one row per block ----------------
__device__ __forceinline__ void ln_body(
    const float* __restrict__ x, const float* __restrict__ gam,
    const float* __restrict__ bet, s16* __restrict__ out, int row, float* red)
{
    int t = threadIdx.x;
    const float4* xr = (const float4*)(x + (size_t)row * HDIM);
    float4 v0 = xr[t], v1 = xr[t + 256];
    float s = v0.x + v0.y + v0.z + v0.w + v1.x + v1.y + v1.z + v1.w;
    #pragma unroll
    for (int m = 1; m < 64; m <<= 1) s += __shfl_xor(s, m);
    int wid = t >> 6, lane = t & 63;
    if (lane == 0) red[wid] = s;
    __syncthreads();
    float mean = (red[0] + red[1] + red[2] + red[3]) * (1.0f / HDIM);
    float d0 = v0.x - mean, d1 = v0.y - mean, d2 = v0.z - mean, d3 = v0.w - mean;
    float d4 = v1.x - mean, d5 = v1.y - mean, d6 = v1.z - mean, d7 = v1.w - mean;
    float vs = d0*d0 + d1*d1 + d2*d2 + d3*d3 + d4*d4 + d5*d5 + d6*d6 + d7*d7;
    #pragma unroll
    for (int m = 1; m < 64; m <<= 1) vs += __shfl_xor(vs, m);
    if (lane == 0) red[4 + wid] = vs;
    __syncthreads();
    float var = (red[4] + red[5] + red[6] + red[7]) * (1.0f / HDIM);
    float rinv = rsqrtf(var + 1e-5f);
    const float4* gm = (const float4*)gam;
    const float4* bt = (const float4*)bet;
    float4 g0 = gm[t], g1 = gm[t + 256], b0 = bt[t], b1 = bt[t + 256];
    s16* orow = out + (size_t)row * HDIM;
    float y0 = d0 * rinv * g0.x + b0.x, y1 = d1 * rinv * g0.y + b0.y;
    float y2 = d2 * rinv * g0.z + b0.z, y3 = d3 * rinv * g0.w + b0.w;
    float y4 = d4 * rinv * g1.x + b1.x, y5 = d5 * rinv * g1.y + b1.y;
    float y6 = d6 * rinv * g1.z + b1.z, y7 = d7 * rinv * g1.w + b1.w;
    uint2 o0, o1;
    o0.x = (unsigned)f2bf(y0) | ((unsigned)f2bf(y1) << 16);
    o0.y = (unsigned)f2bf(y2) | ((unsigned)f2bf(y3) << 16);
    o1.x = (unsigned)f2bf(y4) | ((unsigned)f2bf(y5) << 16);
    o1.y = (unsigned)f2bf(y6) | ((unsigned)f2bf(y7) << 16);
    *(uint2*)(orow + t * 4) = o0;
    *(uint2*)(orow + 1024 + t * 4) = o1;
}

__global__ __launch_bounds__(256) void ln_kernel(
    const float* __restrict__ x, const float* __restrict__ gam,
    const float* __restrict__ bet, s16* __restrict__ out)
{
    __shared__ float red[8];
    ln_body(x, gam, bet, out, blockIdx.x, red);
}

// LN1 + w_attn^T fused: blocks [0,4096) = LN rows; [4096,7168) = transpose tiles (96x32).
__global__ __launch_bounds__(256) void ln1_wattn_kernel(
    const float* __restrict__ x, const float* __restrict__ gam,
    const float* __restrict__ bet, s16* __restrict__ out,
    const float* __restrict__ w, s16* __restrict__ wTo)
{
    __shared__ float tile[64][65];
    int b = blockIdx.x;
    if (b >= 4096) {
        int tid = b - 4096;                  // 0..3071, tiles 96 x 32
        transpose_body256(w, wTo, 2048, 6144, (tid % 96) * 64, (tid / 96) * 64, tile);
        return;
    }
    ln_body(x, gam, bet, out, b, &tile[0][0]);
}

// ============ 2-phase/K-tile BMxBN GEMM (r8-proven, byte-identical) ============
template<int BM, int BN, int EPI>
__global__ __launch_bounds__(512, 2) void gemm2p(
    const s16* __restrict__ A, const s16* __restrict__ Bt,
    const float* __restrict__ bias, int M, int N, int K,
    float* __restrict__ of, const float* __restrict__ resid,
    s16* __restrict__ ob, s16* __restrict__ ob2, s16* __restrict__ ob3)
{
    constexpr int WN  = BN / 64;
    constexpr int WM  = 8 / WN;
    constexpr int MS  = BM / WM;                  // 128|64
    constexpr int NMI = MS / 16;
    constexpr int HF  = NMI / 2;
    constexpr int ABYT = BM * 128;
    constexpr int DBUF = ABYT + BN * 128;
    constexpr bool BIG = (BM == 256 && BN == 256);
    constexpr int VMN = BIG ? 6 : (BN == 256 ? 4 : 2);
    constexpr int LG1 = BIG ? 8 : 4;
    __shared__ __attribute__((aligned(16))) char smem[2 * DBUF];

    int t = threadIdx.x;
    int wid = t >> 6, lane = t & 63;
    int wm = (WN == 4) ? (wid >> 2) : (wid >> 1);
    int wn = (WN == 4) ? (wid & 3) : (wid & 1);
    int c = lane & 15, g = lane >> 4;

    int gx = gridDim.x;
    int wg = blockIdx.y * gx + blockIdx.x;
    int nwg = gx * gridDim.y;
    wg = (wg & 7) * (nwg >> 3) + (wg >> 3);
    int n0 = (wg % gx) * BN;
    int m0 = (wg / gx) * BM;

    float bn[4];
    #pragma unroll
    for (int ni = 0; ni < 4; ++ni) bn[ni] = bias[n0 + wn * 64 + ni * 16 + c];

    int slr = t >> 3;
    int sls = (t & 7) ^ (slr & 7);
    auto stA = [&](int d, int u, int T) {
        gload_lds16(A + (size_t)(m0 + u * 64 + slr) * K + T * 64 + sls * 8,
                    smem + d * DBUF + u * 8192 + t * 16);
    };
    auto stB = [&](int d, int u, int T) {
        gload_lds16(Bt + (size_t)(n0 + u * 64 + slr) * K + T * 64 + sls * 8,
                    smem + d * DBUF + ABYT + u * 8192 + t * 16);
    };
    auto stageSB = [&](int d, int T) {
        if constexpr (BIG) {
            stA(d, 0, T); stA(d, 2, T);
            stB(d, 0, T); stB(d, 1, T); stB(d, 2, T); stB(d, 3, T);
        } else if constexpr (BN == 256) {
            stB(d, 0, T); stB(d, 1, T); stB(d, 2, T); stB(d, 3, T);
        } else {
            stB(d, 0, T); stB(d, 1, T);
        }
    };
    auto stageSA = [&](int d, int T) {
        if constexpr (BIG) { stA(d, 1, T); stA(d, 3, T); }
        else if constexpr (BN == 256) { stA(d, 0, T); stA(d, 1, T); }
        else { stA(d, 0, T); stA(d, 1, T); stA(d, 2, T); stA(d, 3, T); }
    };

    int px0 = ((g) ^ (c & 7)) * 16;
    int px1 = ((4 + g) ^ (c & 7)) * 16;

    f32x4 zero = {0.f, 0.f, 0.f, 0.f};
    f32x4 acc[NMI][4];
    #pragma unroll
    for (int mi = 0; mi < NMI; ++mi)
        #pragma unroll
        for (int ni = 0; ni < 4; ++ni) acc[mi][ni] = zero;

    bf16x8 a0[HF][2], a1[HF][2], bfr[4][2];

#define READ_B(d) { _Pragma("unroll") for (int fn = 0; fn < 4; ++fn) { \
    const char* p_ = smem + (d) * DBUF + ABYT + (wn * 64 + fn * 16 + c) * 128; \
    bfr[fn][0] = *(const bf16x8*)(p_ + px0); \
    bfr[fn][1] = *(const bf16x8*)(p_ + px1); } }
#define READ_A(d, h, arr) { _Pragma("unroll") for (int f = 0; f < HF; ++f) { \
    const char* p_ = smem + (d) * DBUF + (wm * MS + ((h) * HF + f) * 16 + c) * 128; \
    arr[f][0] = *(const bf16x8*)(p_ + px0); \
    arr[f][1] = *(const bf16x8*)(p_ + px1); } }
#define MFMA_H(h, arr) { _Pragma("unroll") for (int f = 0; f < HF; ++f) \
    _Pragma("unroll") for (int ni = 0; ni < 4; ++ni) { \
        acc[(h)*HF+f][ni] = __builtin_amdgcn_mfma_f32_16x16x32_bf16( \
            arr[f][0], bfr[ni][0], acc[(h)*HF+f][ni], 0, 0, 0); \
        acc[(h)*HF+f][ni] = __builtin_amdgcn_mfma_f32_16x16x32_bf16( \
            arr[f][1], bfr[ni][1], acc[(h)*HF+f][ni], 0, 0, 0); } }

    int nk = K >> 6;

    stageSB(0, 0);
    stageSA(0, 0);
    stageSB(1, 1);
    asm volatile("s_waitcnt vmcnt(%0)" :: "i"(VMN) : "memory");
    __builtin_amdgcn_s_barrier();

    for (int T = 0; T < nk; ++T) {
        int d = T & 1;
        bool s1 = (T + 1 < nk), s2 = (T + 2 < nk);
        __builtin_amdgcn_sched_barrier(0);
        READ_B(d) READ_A(d, 0, a0)
        __builtin_amdgcn_sched_barrier(0);
        READ_A(d, 1, a1)
        if (s1) stageSA(d ^ 1, T + 1);
        asm volatile("s_waitcnt lgkmcnt(%0)" :: "i"(LG1) : "memory");
        __builtin_amdgcn_sched_barrier(0);
        __builtin_amdgcn_s_setprio(1);
        MFMA_H(0, a0)
        __builtin_amdgcn_s_setprio(0);
        __builtin_amdgcn_s_barrier();
        __builtin_amdgcn_sched_barrier(0);
        if (s2) stageSB(d, T + 2);
        asm volatile("s_waitcnt lgkmcnt(0)" ::: "memory");
        __builtin_amdgcn_sched_barrier(0);
        __builtin_amdgcn_s_setprio(1);
        MFMA_H(1, a1)
        __builtin_amdgcn_s_setprio(0);
        if (s2) { asm volatile("s_waitcnt vmcnt(%0)" :: "i"(VMN) : "memory"); }
        else    { asm volatile("s_waitcnt vmcnt(0)" ::: "memory"); }
        __builtin_amdgcn_s_barrier();
        __builtin_amdgcn_sched_barrier(0);
    }
#undef READ_B
#undef READ_A
#undef MFMA_H

    if constexpr (EPI == 0) {
        constexpr int ROWG = BM / 64;
        int part = n0 >> 11;
        int hh0 = (n0 & 2047) >> 7;
        int bb = m0 >> 11;
        int tt0 = m0 & 2047;
        s16* LT = (s16*)smem;           // 64 x 264 bounce
        #pragma unroll
        for (int q2 = 0; q2 < ROWG; ++q2) {
            if (q2) __syncthreads();
            bool sel = (MS == 128) ? (wm == (q2 >> 1)) : (wm == q2);
            int fb = (MS == 128) ? (q2 & 1) * 4 : 0;
            if (sel) {
                #pragma unroll
                for (int f = 0; f < 4; ++f)
                    #pragma unroll
                    for (int ni = 0; ni < 4; ++ni)
                        #pragma unroll
                        for (int j = 0; j < 4; ++j)
                            LT[(f * 16 + g * 4 + j) * 264 + wn * 64 + ni * 16 + c] =
                                (s16)f2bf(acc[fb + f][ni][j] + bn[ni]);
            }
            __syncthreads();
            if (part < 2) {
                s16* dst = (part == 0 ? ob : ob2);
                int rr = t >> 3, c0 = (t & 7) * 32;
                int hh = hh0 + (c0 >> 7);
                size_t base = (((size_t)(bb * NHEAD + hh)) * TSEQ + tt0 + q2 * 64 + rr) * HDHEAD + (c0 & 127);
                #pragma unroll
                for (int k2 = 0; k2 < 4; ++k2)
                    *(bf16x8*)(dst + base + k2 * 8) = *(const bf16x8*)(LT + rr * 264 + c0 + k2 * 8);
            } else {
                int ddl = t >> 1, half = t & 1;
                int hh = hh0 + (ddl >> 7);
                size_t base = (((size_t)(bb * NHEAD + hh)) * HDHEAD + (ddl & 127)) * TSEQ + tt0 + q2 * 64 + half * 32;
                #pragma unroll
                for (int k2 = 0; k2 < 4; ++k2) {
                    union { s16 v[8]; bf16x8 x; } u;
                    #pragma unroll
                    for (int e = 0; e < 8; ++e) u.v[e] = LT[(half * 32 + k2 * 8 + e) * 264 + ddl];
                    *(bf16x8*)(ob3 + base + k2 * 8) = u.x;
                }
            }
        }
    } else {
        #pragma unroll
        for (int mi = 0; mi < NMI; ++mi) {
            #pragma unroll
            for (int ni = 0; ni < 4; ++ni) {
                int n = n0 + wn * 64 + ni * 16 + c;
                #pragma unroll
                for (int j = 0; j < 4; ++j) {
                    int m = m0 + wm * MS + mi * 16 + g * 4 + j;
                    float val = acc[mi][ni][j] + bn[ni];
                    if constexpr (EPI == 1) {
                        size_t idx = (size_t)m * N + n;
                        of[idx] = val + resid[idx];
                    } else {
                        float zz = 1.5957691216057308f * (val + 0.044715f * val * val * val);
                        float ge = val / (1.0f + __expf(-zz));
                        ob[(size_t)m * N + n] = (s16)f2bf(ge);
                    }
                }
            }
        }
    }
}

// ---------------- causal flash attention + fused weight transposes ----------------
__global__ __launch_bounds__(512) void attn_kernel(
    const s16* __restrict__ qb, const s16* __restrict__ kbf,
    const s16* __restrict__ vbf, s16* __restrict__ yb,
    const float* __restrict__ w1, s16* __restrict__ w1T, int n1,
    const float* __restrict__ w2, s16* __restrict__ w2T, int n2,
    const float* __restrict__ w3, s16* __restrict__ w3T)
{
    __shared__ __attribute__((aligned(16))) char sm[32768];
    s16* Kl = (s16*)sm;
    s16* Vl = (s16*)(sm + 16384);
    int fid = blockIdx.x;
    if (fid >= 512) {
        float (*tile)[65] = (float (*)[65])sm;
        fid -= 512;
        if (fid < n1)           transpose512(w1, w1T, 2048, 2048, fid, tile);
        else if (fid < n1 + n2) transpose512(w2, w2T, 2048, 8192, fid - n1, tile);
        else                    transpose512(w3, w3T, 8192, 2048, fid - n1 - n2, tile);
        return;
    }
    int bid = ((fid & 7) << 6) | (fid >> 3);     // XCD swizzle (512 blocks)
    int qt2 = 15 - (bid & 15);                   // descending: longest blocks first
    int bh = bid >> 4;
    int q0 = qt2 << 7;
    int t = threadIdx.x;
    int wid = t >> 6, lane = t & 63;
    int c = lane & 15, g = lane >> 4;

    const s16* qrow = qb + ((size_t)bh * TSEQ + q0 + wid * 16 + c) * HDHEAD;
    bf16x8 qf[4];
    #pragma unroll
    for (int ds = 0; ds < 4; ++ds) qf[ds] = *(const bf16x8*)(qrow + ds * 32 + g * 8);

    f32x4 zero = {0.f, 0.f, 0.f, 0.f};
    f32x4 acc_o[8];
    #pragma unroll
    for (int o = 0; o < 8; ++o) acc_o[o] = zero;
    float mrun = -INFINITY, lrun = 0.0f;
    const float sc = 0.08838834764831843f;

    int tr = t >> 4, tcb = (t & 15) << 4;
    int vr = t >> 3, vcb = (t & 7) << 4;
    const s16* ksrc = kbf + (size_t)bh * TSEQ * HDHEAD;
    const s16* vsrc = vbf + (size_t)bh * HDHEAD * TSEQ;
    int qg = q0 + wid * 16 + c;
    int ktmax = 2 * qt2 + 1;

    for (int kt = 0; kt <= ktmax; ++kt) {
        __syncthreads();
        #pragma unroll
        for (int rr = 0; rr < 2; ++rr) {
            int row = tr + rr * 32;
            bf16x8 kv = *(const bf16x8*)(ksrc + (size_t)(kt * 64 + row) * HDHEAD + (tcb >> 1));
            *(bf16x8*)((char*)Kl + row * 256 + (tcb ^ ((row & 7) << 4))) = kv;
        }
        #pragma unroll
        for (int rr = 0; rr < 2; ++rr) {
            int row = vr + rr * 64;
            bf16x8 vv = *(const bf16x8*)(vsrc + (size_t)row * TSEQ + kt * 64 + (vcb >> 1));
            *(bf16x8*)((char*)Vl + row * 128 + (vcb ^ ((row & 7) << 4))) = vv;
        }
        __syncthreads();

        f32x4 sacc[4];
        #pragma unroll
        for (int kb2 = 0; kb2 < 4; ++kb2) sacc[kb2] = zero;
        __builtin_amdgcn_s_setprio(1);
        #pragma unroll
        for (int ds = 0; ds < 4; ++ds) {
            #pragma unroll
            for (int kb2 = 0; kb2 < 4; ++kb2) {
                int krow = kb2 * 16 + c;
                bf16x8 kf = *(const bf16x8*)((char*)Kl + krow * 256 +
                                ((ds * 64 + g * 16) ^ ((krow & 7) << 4)));
                sacc[kb2] = __builtin_amdgcn_mfma_f32_16x16x32_bf16(kf, qf[ds], sacc[kb2], 0, 0, 0);
            }
        }
        __builtin_amdgcn_s_setprio(0);
        float pv[16];
        float mt = -INFINITY;
        bool diag = (kt * 64 + 63 > qg);
        #pragma unroll
        for (int kb2 = 0; kb2 < 4; ++kb2) {
            #pragma unroll
            for (int j = 0; j < 4; ++j) {
                float s = sacc[kb2][j] * sc;
                if (diag && (kt * 64 + kb2 * 16 + g * 4 + j) > qg) s = -INFINITY;
                pv[kb2 * 4 + j] = s;
                mt = fmaxf(mt, s);
            }
        }
        mt = fmaxf(mt, __shfl_xor(mt, 16));
        mt = fmaxf(mt, __shfl_xor(mt, 32));
        if (!__all(mt - mrun <= 8.0f)) {
            float mnew = fmaxf(mrun, mt);
            float corr = __expf(mrun - mnew);
            #pragma unroll
            for (int o = 0; o < 8; ++o)
                #pragma unroll
                for (int j = 0; j < 4; ++j) acc_o[o][j] *= corr;
            lrun *= corr;
            mrun = mnew;
        }
        float ls = 0.0f;
        #pragma unroll
        for (int i = 0; i < 16; ++i) { float p = __expf(pv[i] - mrun); pv[i] = p; ls += p; }
        ls += __shfl_xor(ls, 16);
        ls += __shfl_xor(ls, 32);
        lrun += ls;

        unsigned dpk[8];
        #pragma unroll
        for (int kb2 = 0; kb2 < 4; ++kb2) {
            dpk[kb2 * 2]     = (unsigned)f2bf(pv[kb2 * 4 + 0]) | ((unsigned)f2bf(pv[kb2 * 4 + 1]) << 16);
            dpk[kb2 * 2 + 1] = (unsigned)f2bf(pv[kb2 * 4 + 2]) | ((unsigned)f2bf(pv[kb2 * 4 + 3]) << 16);
        }
        int srcA = ((g & 1) << 5) + c;
        int srcB = srcA + 16;
        #pragma unroll
        for (int s2 = 0; s2 < 2; ++s2) {
            unsigned lo0 = (unsigned)__shfl((int)dpk[(2 * s2) * 2 + 0], srcA);
            unsigned hi0 = (unsigned)__shfl((int)dpk[(2 * s2 + 1) * 2 + 0], srcA);
            unsigned lo1 = (unsigned)__shfl((int)dpk[(2 * s2) * 2 + 1], srcA);
            unsigned hi1 = (unsigned)__shfl((int)dpk[(2 * s2 + 1) * 2 + 1], srcA);
            unsigned lo2 = (unsigned)__shfl((int)dpk[(2 * s2) * 2 + 0], srcB);
            unsigned hi2 = (unsigned)__shfl((int)dpk[(2 * s2 + 1) * 2 + 0], srcB);
            unsigned lo3 = (unsigned)__shfl((int)dpk[(2 * s2) * 2 + 1], srcB);
            unsigned hi3 = (unsigned)__shfl((int)dpk[(2 * s2 + 1) * 2 + 1], srcB);
            union { unsigned u[4]; bf16x8 v; } pf;
            pf.u[0] = (g < 2) ? lo0 : hi0;
            pf.u[1] = (g < 2) ? lo1 : hi1;
            pf.u[2] = (g < 2) ? lo2 : hi2;
            pf.u[3] = (g < 2) ? lo3 : hi3;
            __builtin_amdgcn_s_setprio(1);
            #pragma unroll
            for (int o = 0; o < 8; ++o) {
                int vrow = o * 16 + c;
                bf16x8 vf = *(const bf16x8*)((char*)Vl + vrow * 128 +
                                ((s2 * 64 + g * 16) ^ ((vrow & 7) << 4)));
                acc_o[o] = __builtin_amdgcn_mfma_f32_16x16x32_bf16(vf, pf.v, acc_o[o], 0, 0, 0);
            }
            __builtin_amdgcn_s_setprio(0);
        }
    }

    float inv = 1.0f / lrun;
    int bb = bh >> 4, hh = bh & 15;
    s16* yp = yb + ((size_t)bb * TSEQ + q0 + wid * 16 + c) * HDIM + hh * HDHEAD;
    #pragma unroll
    for (int o = 0; o < 8; ++o) {
        int d = o * 16 + g * 4;
        unsigned p0 = (unsigned)f2bf(acc_o[o][0] * inv) | ((unsigned)f2bf(acc_o[o][1] * inv) << 16);
        unsigned p1 = (unsigned)f2bf(acc_o[o][2] * inv) | ((unsigned)f2bf(acc_o[o][3] * inv) << 16);
        *(unsigned*)(yp + d) = p0;
        *(unsigned*)(yp + d + 2) = p1;
    }
}

extern "C" void kernel_launch(void* const* d_in, const int* in_sizes, int n_in,
                              void* d_out, int out_size, void* d_ws, size_t ws_size,
                              hipStream_t stream)
{
    const float* x     = (const float*)d_in[0];
    const float* ln1g  = (const float*)d_in[1];
    const float* ln1b  = (const float*)d_in[2];
    const float* wattn = (const float*)d_in[3];
    const float* battn = (const float*)d_in[4];
    const float* wproj = (const float*)d_in[5];
    const float* bproj = (const float*)d_in[6];
    const float* ln2g  = (const float*)d_in[7];
    const float* ln2b  = (const float*)d_in[8];
    const float* wfc   = (const float*)d_in[9];
    const float* bfc   = (const float*)d_in[10];
    const float* wfc2  = (const float*)d_in[11];
    const float* bfc2  = (const float*)d_in[12];
    float* out = (float*)d_out;

    s16* ws   = (s16*)d_ws;
    s16* wT   = ws;                        // [0, 16777216): w_attn^T, then w_fc^T
    s16* qbuf = wT + 16777216;             // [16777216, 25165824)
    s16* kbuf = qbuf + 8388608;            // [25165824, 33554432)
    s16* vbuf = kbuf + 8388608;            // [33554432, 41943040)
    s16* hbuf = vbuf + 8388608;            // [41943040, 50331648)
    s16* ybuf  = hbuf;
    s16* h2buf = qbuf;
    s16* gbuf  = kbuf;                     // gelu out spans [25165824, 58720256)

    const size_t NEED = (58720256ull + 16777216ull) * 2;   // 151.0 MB
    bool big = (ws_size >= NEED);
    s16* wTp  = big ? hbuf + 8388608 : wT;   // [50331648, 54525952) — dead before fc writes gbuf
    s16* wTf2 = big ? ws + 58720256  : wT;   // [58720256, 75497472) — disjoint from gbuf
    s16* wTfc = wT;                          // w_attn^T slot, dead after QKV

    // 1) LN1 + w_attn^T fused (independent BW work, both complete before QKV)
    ln1_wattn_kernel<<<4096 + 3072, 256, 0, stream>>>(x, ln1g, ln1b, hbuf, wattn, wT);
    // 2) QKV GEMM (scatter q/k/v, v transposed)
    gemm2p<128, 256, 0><<<dim3(24, 32), 512, 0, stream>>>(
        hbuf, wT, battn, MTOK, 6144, 2048, nullptr, nullptr, qbuf, kbuf, vbuf);
    // 3) attention (+ fused w_proj/w_fc/w_fc2 transposes when ws allows)
    if (big) {
        attn_kernel<<<512 + 1024 + 4096 + 4096, 512, 0, stream>>>(
            qbuf, kbuf, vbuf, ybuf,
            wproj, wTp, 1024, wfc, wTfc, 4096, wfc2, wTf2);
    } else {
        attn_kernel<<<512, 512, 0, stream>>>(
            qbuf, kbuf, vbuf, ybuf,
            nullptr, nullptr, 0, nullptr, nullptr, 0, nullptr, nullptr);
    }
    // 4) proj (+residual, fp32 -> d_out)
    if (!big) transpose_convert<<<dim3(32, 32), 256, 0, stream>>>(wproj, wTp, 2048, 2048);
    gemm2p<256, 128, 1><<<dim3(16, 16), 512, 0, stream>>>(
        ybuf, wTp, bproj, MTOK, 2048, 2048, out, x, nullptr, nullptr, nullptr);
    // 5) LN2
    ln_kernel<<<4096, 256, 0, stream>>>(out, ln2g, ln2b, h2buf);
    // 6) fc (+gelu, bf16)
    if (!big) transpose_convert<<<dim3(128, 32), 256, 0, stream>>>(wfc, wTfc, 2048, 8192);
    gemm2p<256, 256, 2><<<dim3(32, 16), 512, 0, stream>>>(
        h2buf, wTfc, bfc, MTOK, 8192, 2048, nullptr, nullptr, gbuf, nullptr, nullptr);
    // 7) fc2 (+residual, fp32; reads+overwrites d_out per-element)
    if (!big) transpose_convert<<<dim3(32, 128), 256, 0, stream>>>(wfc2, wTf2, 8192, 2048);
    gemm2p<256, 128, 1><<<dim3(16, 16), 512, 0, stream>>>(
        gbuf, wTf2, bfc2, MTOK, 2048, 8192, out, out, nullptr, nullptr, nullptr);
}